// Round 2
// baseline (266.446 us; speedup 1.0000x reference)
//
#include <hip/hip_runtime.h>

// QuantumAttentionMechanism on MI355X (gfx950)
// B=4, S=1024, D=1024, H=16, NQ=8, HEAD_DIM=64, ALPHA=0.7
//
// Math simplifications (exact up to fp rounding):
//   classical.mean(h) = (Q . K over full D) / (H*sqrt(HEAD_DIM)) = dot/128
//   entropy(i,j) = log(Z) - (Sa_i + Sb_j)/Z,  Z = A_i + B_j
//     with A_i = sum_m exp(tanh(q[i,m])), Sa_i = sum_m exp(e)*e  (m<8), same for key rows.
//   attended = attn @ V (full D), output = attended @ Wo^T + bo.

typedef float f32x4 __attribute__((ext_vector_type(4)));
typedef short s16x8 __attribute__((ext_vector_type(8)));
typedef unsigned short u16;

#define Bc 4
#define Sc 1024
#define Dc 1024
#define NTOK (Bc * Sc)          // 4096
#define CSCALE (0.7f / 128.0f)  // ALPHA / (H*sqrt(HEAD_DIM))
#define ESCALE 0.3f             // 1-ALPHA

typedef void __attribute__((address_space(1))) as1_void;
typedef void __attribute__((address_space(3))) as3_void;

__device__ __forceinline__ u16 f2b(float f) {  // fp32 -> bf16 RNE
  union { float f; unsigned u; } v; v.f = f;
  unsigned r = v.u + 0x7fffu + ((v.u >> 16) & 1u);
  return (u16)(r >> 16);
}

// ---------------- cast fp32 -> bf16, vectorized ----------------
__global__ __launch_bounds__(256) void cast_bf16(const float* __restrict__ in,
                                                 u16* __restrict__ out, int n4) {
  int i = blockIdx.x * 256 + threadIdx.x;
  if (i >= n4) return;
  float4 v = reinterpret_cast<const float4*>(in)[i];
  ushort4 o = make_ushort4(f2b(v.x), f2b(v.y), f2b(v.z), f2b(v.w));
  reinterpret_cast<ushort4*>(out)[i] = o;
}

// ---------------- per-row entropy aggregates ----------------
// agg layout: qA[NTOK], qS[NTOK], kA[NTOK], kS[NTOK]
__global__ __launch_bounds__(256) void ent_agg(const float* __restrict__ q,
                                               const float* __restrict__ k,
                                               float* __restrict__ agg) {
  int r = blockIdx.x * 256 + threadIdx.x;
  if (r >= 2 * NTOK) return;
  const float* src = (r < NTOK) ? (q + (size_t)r * Dc) : (k + (size_t)(r - NTOK) * Dc);
  float A = 0.f, Sv = 0.f;
#pragma unroll
  for (int m = 0; m < 8; ++m) {
    float e = tanhf(src[m]);
    float a = __expf(e);
    A += a; Sv += a * e;
  }
  if (r < NTOK) { agg[r] = A; agg[NTOK + r] = Sv; }
  else          { agg[NTOK + r] = A; agg[3 * NTOK + (r - NTOK)] = Sv; }
  // r>=NTOK: kA lands at agg[2*NTOK + (r-NTOK)], kS at agg[3*NTOK + (r-NTOK)].
}

// ---------------- m97-style bf16 GEMM core: C[128x128] = A[M,K] * Bt[N,K]^T ----------------
// 256 threads (4 waves, 2x2), BK=32, 16x16x32 bf16 MFMA, global_load_lds 16B.
__device__ __forceinline__ void gemm_core(const u16* __restrict__ A, const u16* __restrict__ Bt,
                                          int K, int row0, int col0,
                                          u16* lA, u16* lB, f32x4 acc[4][4]) {
  const int tid  = threadIdx.x;
  const int lane = tid & 63;
  const int wave = tid >> 6;
  const int wm = (wave >> 1) * 64;
  const int wn = (wave & 1) * 64;
  const int fr = lane & 15;        // A-row / B-col within 16
  const int ks = (lane >> 4) * 8;  // k-slice
  for (int kt = 0; kt < K; kt += 32) {
#pragma unroll
    for (int it = 0; it < 2; ++it) {
      const int ci = it * 256 + tid;       // 16B chunk index, 512 chunks/tile
      const int r  = ci >> 2;              // tile row (0..127)
      const int cb = (ci & 3) * 8;         // col offset in elements
      __builtin_amdgcn_global_load_lds((const as1_void*)(A + (size_t)(row0 + r) * K + (kt + cb)),
                                       (as3_void*)(lA + ci * 8), 16, 0, 0);
      __builtin_amdgcn_global_load_lds((const as1_void*)(Bt + (size_t)(col0 + r) * K + (kt + cb)),
                                       (as3_void*)(lB + ci * 8), 16, 0, 0);
    }
    __syncthreads();
    s16x8 af[4], bf[4];
#pragma unroll
    for (int i = 0; i < 4; ++i) {
      af[i] = *reinterpret_cast<const s16x8*>(lA + (wm + i * 16 + fr) * 32 + ks);
      bf[i] = *reinterpret_cast<const s16x8*>(lB + (wn + i * 16 + fr) * 32 + ks);
    }
#pragma unroll
    for (int i = 0; i < 4; ++i)
#pragma unroll
      for (int j = 0; j < 4; ++j)
        acc[i][j] = __builtin_amdgcn_mfma_f32_16x16x32_bf16(af[i], bf[j], acc[i][j], 0, 0, 0);
    __syncthreads();
  }
}

// ---------------- QKV projections (z=0:Q, 1:K, 2:V-transposed) ----------------
__global__ __launch_bounds__(256) void gemm_proj(const u16* __restrict__ Xall,  // qx,kx,vx contiguous
                                                 const u16* __restrict__ Wall,  // wq,wk,wv contiguous
                                                 const float* __restrict__ biasq,
                                                 const float* __restrict__ biask,
                                                 const float* __restrict__ biasv,
                                                 u16* __restrict__ QKout,       // Qb,Kb contiguous
                                                 u16* __restrict__ Vt) {        // [Bc][Dc][Sc]
  __shared__ __align__(16) u16 lA[128 * 32];
  __shared__ __align__(16) u16 lB[128 * 32];
  const int z = blockIdx.z;
  const int row0 = blockIdx.x * 128, col0 = blockIdx.y * 128;
  const u16* A  = Xall + (size_t)z * NTOK * Dc;
  const u16* Bt = Wall + (size_t)z * Dc * Dc;
  f32x4 acc[4][4] = {};
  gemm_core(A, Bt, Dc, row0, col0, lA, lB, acc);

  const int lane = threadIdx.x & 63, wave = threadIdx.x >> 6;
  const int wm = (wave >> 1) * 64, wn = (wave & 1) * 64;
  const int cr = (lane >> 4) * 4, cc = lane & 15;
  const float* bias = (z == 0) ? biasq : (z == 1) ? biask : biasv;
#pragma unroll
  for (int j = 0; j < 4; ++j) {
    const int gc = col0 + wn + j * 16 + cc;
    const float bb = bias[gc];
#pragma unroll
    for (int i = 0; i < 4; ++i) {
      const int gr = row0 + wm + i * 16 + cr;
      f32x4 v = acc[i][j];
      if (z < 2) {
        u16* dst = QKout + (size_t)z * NTOK * Dc + (size_t)gr * Dc + gc;
#pragma unroll
        for (int r = 0; r < 4; ++r) dst[(size_t)r * Dc] = f2b(v[r] + bb);
      } else {
        const int b = gr >> 10, t = gr & (Sc - 1);  // t multiple of 4
        ushort4 o = make_ushort4(f2b(v[0] + bb), f2b(v[1] + bb), f2b(v[2] + bb), f2b(v[3] + bb));
        *reinterpret_cast<ushort4*>(Vt + (size_t)b * Dc * Sc + (size_t)gc * Sc + t) = o;
      }
    }
  }
}

// ---------------- scores GEMM + entropy epilogue -> combined fp32 ----------------
__global__ __launch_bounds__(256) void gemm_scores(const u16* __restrict__ Qb,
                                                   const u16* __restrict__ Kb,
                                                   const float* __restrict__ agg,
                                                   float* __restrict__ comb) {
  __shared__ __align__(16) u16 lA[128 * 32];
  __shared__ __align__(16) u16 lB[128 * 32];
  const int z = blockIdx.z;
  const int row0 = blockIdx.x * 128, col0 = blockIdx.y * 128;
  const u16* A  = Qb + (size_t)z * Sc * Dc;
  const u16* Bt = Kb + (size_t)z * Sc * Dc;
  f32x4 acc[4][4] = {};
  gemm_core(A, Bt, Dc, row0, col0, lA, lB, acc);

  const int lane = threadIdx.x & 63, wave = threadIdx.x >> 6;
  const int wm = (wave >> 1) * 64, wn = (wave & 1) * 64;
  const int cr = (lane >> 4) * 4, cc = lane & 15;
  const float* qA = agg + (size_t)z * Sc;
  const float* qS = agg + NTOK + (size_t)z * Sc;
  const float* kA = agg + 2 * NTOK + (size_t)z * Sc;
  const float* kS = agg + 3 * NTOK + (size_t)z * Sc;
  float* C = comb + (size_t)z * Sc * Sc;
#pragma unroll
  for (int j = 0; j < 4; ++j) {
    const int gc = col0 + wn + j * 16 + cc;
    const float kAv = kA[gc], kSv = kS[gc];
#pragma unroll
    for (int i = 0; i < 4; ++i) {
      const int gr = row0 + wm + i * 16 + cr;
      f32x4 v = acc[i][j];
#pragma unroll
      for (int r = 0; r < 4; ++r) {
        const int s = gr + r;
        const float Z = qA[s] + kAv;
        const float ent = __logf(Z) - (qS[s] + kSv) / Z;
        C[(size_t)s * Sc + gc] = CSCALE * v[r] + ESCALE * ent;
      }
    }
  }
}

// ---------------- row softmax: comb -> attn fp32 (d_out) + attn bf16 (ws) ----------------
__global__ __launch_bounds__(256) void softmax_row(const float* __restrict__ comb,
                                                   float* __restrict__ attn_f,
                                                   u16* __restrict__ attn_b) {
  const int row = blockIdx.x;  // 0..NTOK-1
  const int t = threadIdx.x;
  const float* src = comb + (size_t)row * Sc;
  float4 v = reinterpret_cast<const float4*>(src)[t];
  float m = fmaxf(fmaxf(v.x, v.y), fmaxf(v.z, v.w));
#pragma unroll
  for (int off = 1; off < 64; off <<= 1) m = fmaxf(m, __shfl_xor(m, off));
  __shared__ float red[8];
  if ((t & 63) == 0) red[t >> 6] = m;
  __syncthreads();
  m = fmaxf(fmaxf(red[0], red[1]), fmaxf(red[2], red[3]));
  float e0 = __expf(v.x - m), e1 = __expf(v.y - m), e2 = __expf(v.z - m), e3 = __expf(v.w - m);
  float s = e0 + e1 + e2 + e3;
#pragma unroll
  for (int off = 1; off < 64; off <<= 1) s += __shfl_xor(s, off);
  if ((t & 63) == 0) red[4 + (t >> 6)] = s;
  __syncthreads();
  s = red[4] + red[5] + red[6] + red[7];
  const float inv = 1.f / s;
  float4 o = make_float4(e0 * inv, e1 * inv, e2 * inv, e3 * inv);
  reinterpret_cast<float4*>(attn_f + (size_t)row * Sc)[t] = o;
  ushort4 ob = make_ushort4(f2b(o.x), f2b(o.y), f2b(o.z), f2b(o.w));
  reinterpret_cast<ushort4*>(attn_b + (size_t)row * Sc)[t] = ob;
}

// ---------------- attended = attn @ V  (Bt = Vt[b][d][t]) ----------------
__global__ __launch_bounds__(256) void gemm_av(const u16* __restrict__ attnb,
                                               const u16* __restrict__ Vt,
                                               u16* __restrict__ att) {
  __shared__ __align__(16) u16 lA[128 * 32];
  __shared__ __align__(16) u16 lB[128 * 32];
  const int z = blockIdx.z;
  const int row0 = blockIdx.x * 128, col0 = blockIdx.y * 128;
  const u16* A  = attnb + (size_t)z * Sc * Sc;
  const u16* Bt = Vt + (size_t)z * Dc * Sc;
  f32x4 acc[4][4] = {};
  gemm_core(A, Bt, Sc, row0, col0, lA, lB, acc);

  const int lane = threadIdx.x & 63, wave = threadIdx.x >> 6;
  const int wm = (wave >> 1) * 64, wn = (wave & 1) * 64;
  const int cr = (lane >> 4) * 4, cc = lane & 15;
  u16* C = att + (size_t)z * Sc * Dc;
#pragma unroll
  for (int j = 0; j < 4; ++j) {
    const int gc = col0 + wn + j * 16 + cc;
#pragma unroll
    for (int i = 0; i < 4; ++i) {
      const int gr = row0 + wm + i * 16 + cr;
      f32x4 v = acc[i][j];
#pragma unroll
      for (int r = 0; r < 4; ++r) C[(size_t)(gr + r) * Dc + gc] = f2b(v[r]);
    }
  }
}

// ---------------- output = attended @ Wo^T + bo -> fp32 d_out ----------------
__global__ __launch_bounds__(256) void gemm_out(const u16* __restrict__ att,
                                                const u16* __restrict__ Wob,
                                                const float* __restrict__ bo,
                                                float* __restrict__ out) {
  __shared__ __align__(16) u16 lA[128 * 32];
  __shared__ __align__(16) u16 lB[128 * 32];
  const int row0 = blockIdx.x * 128, col0 = blockIdx.y * 128;
  f32x4 acc[4][4] = {};
  gemm_core(att, Wob, Dc, row0, col0, lA, lB, acc);

  const int lane = threadIdx.x & 63, wave = threadIdx.x >> 6;
  const int wm = (wave >> 1) * 64, wn = (wave & 1) * 64;
  const int cr = (lane >> 4) * 4, cc = lane & 15;
#pragma unroll
  for (int j = 0; j < 4; ++j) {
    const int gc = col0 + wn + j * 16 + cc;
    const float bb = bo[gc];
#pragma unroll
    for (int i = 0; i < 4; ++i) {
      const int gr = row0 + wm + i * 16 + cr;
      f32x4 v = acc[i][j];
#pragma unroll
      for (int r = 0; r < 4; ++r) out[(size_t)(gr + r) * Dc + gc] = v[r] + bb;
    }
  }
}

extern "C" void kernel_launch(void* const* d_in, const int* in_sizes, int n_in,
                              void* d_out, int out_size, void* d_ws, size_t ws_size,
                              hipStream_t stream) {
  const float* query = (const float*)d_in[0];
  const float* key   = (const float*)d_in[1];
  const float* value = (const float*)d_in[2];
  const float* Wq = (const float*)d_in[3];
  const float* bq = (const float*)d_in[4];
  const float* Wk = (const float*)d_in[5];
  const float* bk = (const float*)d_in[6];
  const float* Wv = (const float*)d_in[7];
  const float* bv = (const float*)d_in[8];
  const float* Wo = (const float*)d_in[9];
  const float* bo = (const float*)d_in[10];

  float* out    = (float*)d_out;                    // [B,S,D]
  float* attn_f = out + (size_t)NTOK * Dc;          // [B,S,S]

  char* w = (char*)d_ws;
  const size_t MB = 1ull << 20;
  // Lifetime-overlaid layout (~56 MB total):
  //  [0,24)MB : qx,kx,vx (phases 1-3); then comb fp32 [0,16) + attnb [16,24)
  //  [24,40)MB: Qb,Kb (3-4); then attended overlays [24,32)
  //  [40,48)MB: Vt
  //  [48,56)MB: Wq,Wk,Wv,Wo bf16
  //  [56,..)  : entropy aggregates (64 KB)
  u16* qx = (u16*)(w);
  u16* kx = (u16*)(w + 8 * MB);
  u16* vx = (u16*)(w + 16 * MB);
  float* comb = (float*)(w);
  u16* attnb  = (u16*)(w + 16 * MB);
  u16* Qb = (u16*)(w + 24 * MB);            // Kb = Qb + NTOK*Dc
  u16* attended = (u16*)(w + 24 * MB);
  u16* Vt = (u16*)(w + 40 * MB);
  u16* Wb = (u16*)(w + 48 * MB);            // wq,wk,wv,wo contiguous (2MB each)
  float* agg = (float*)(w + 56 * MB);

  const int n4tok = NTOK * Dc / 4;  // 1048576
  const int n4w   = Dc * Dc / 4;    // 262144

  // 1. casts
  cast_bf16<<<n4tok / 256, 256, 0, stream>>>(query, qx, n4tok);
  cast_bf16<<<n4tok / 256, 256, 0, stream>>>(key,   kx, n4tok);
  cast_bf16<<<n4tok / 256, 256, 0, stream>>>(value, vx, n4tok);
  cast_bf16<<<n4w / 256, 256, 0, stream>>>(Wq, Wb + 0ull * Dc * Dc, n4w);
  cast_bf16<<<n4w / 256, 256, 0, stream>>>(Wk, Wb + 1ull * Dc * Dc, n4w);
  cast_bf16<<<n4w / 256, 256, 0, stream>>>(Wv, Wb + 2ull * Dc * Dc, n4w);
  cast_bf16<<<n4w / 256, 256, 0, stream>>>(Wo, Wb + 3ull * Dc * Dc, n4w);

  // 2. entropy row aggregates
  ent_agg<<<(2 * NTOK) / 256, 256, 0, stream>>>(query, key, agg);

  // 3. Q/K/V projections (z=0,1,2), V written transposed
  gemm_proj<<<dim3(NTOK / 128, Dc / 128, 3), 256, 0, stream>>>(qx, Wb, bq, bk, bv, Qb, Vt);

  // 4. combined scores (classical/128*0.7 + 0.3*entropy)
  gemm_scores<<<dim3(Sc / 128, Sc / 128, Bc), 256, 0, stream>>>(Qb, Qb + (size_t)NTOK * Dc, agg, comb);

  // 5. softmax rows -> attn (fp32 to d_out, bf16 to ws)
  softmax_row<<<NTOK, 256, 0, stream>>>(comb, attn_f, attnb);

  // 6. attended = attn @ V
  gemm_av<<<dim3(Sc / 128, Dc / 128, Bc), 256, 0, stream>>>(attnb, Vt, attended);

  // 7. output = attended @ Wo^T + bo
  gemm_out<<<dim3(NTOK / 128, Dc / 128, 1), 256, 0, stream>>>(attended, Wb + 3ull * Dc * Dc, bo, out);

  (void)in_sizes; (void)n_in; (void)out_size; (void)ws_size;
}